// Round 13
// baseline (569.509 us; speedup 1.0000x reference)
//
#include <hip/hip_runtime.h>
#include <hip/hip_bf16.h>
#include <math.h>

#define Bsz 1024
#define Nn  11
#define Ff  512
#define Zi  10
#define G3  1536

typedef __attribute__((ext_vector_type(8))) short bfrag;
typedef __attribute__((ext_vector_type(16))) float f32x16;

__device__ __forceinline__ unsigned f2bf(float f) {
    __hip_bfloat16 h = __float2bfloat16(f);
    return (unsigned)*reinterpret_cast<unsigned short*>(&h);
}
__device__ __forceinline__ uint4 pack8(float v0, float v1, float v2, float v3,
                                       float v4, float v5, float v6, float v7) {
    uint4 pk;
    pk.x = f2bf(v0) | (f2bf(v1) << 16);
    pk.y = f2bf(v2) | (f2bf(v3) << 16);
    pk.z = f2bf(v4) | (f2bf(v5) << 16);
    pk.w = f2bf(v6) | (f2bf(v7) << 16);
    return pk;
}
__device__ __forceinline__ void pair_decode(int mode, int p, int& pi, int& pj) {
    if (mode == 0) { int r = p, i = 0; while (r >= Nn - i) { r -= Nn - i; ++i; } pi = i; pj = i + r; }
    else { pi = p; pj = Zi; }
}
// async global->LDS, 16B/lane; dst must be wave-uniform base (+lane*16 by HW)
__device__ __forceinline__ void gl_lds16(const void* src, void* dst) {
    __builtin_amdgcn_global_load_lds((const __attribute__((address_space(1))) void*)src,
                                     (__attribute__((address_space(3))) void*)dst, 16, 0, 0);
}

// ---------------------------------------------------------------------------
__global__ void init_col_kernel(const float* __restrict__ nf, float* __restrict__ col) {
    int idx = blockIdx.x * 256 + threadIdx.x;
    int b = idx >> 9, f = idx & 511;
    col[idx] = nf[(b * Nn + Zi) * Ff + f];
}

// ---------------------------------------------------------------------------
// pack fp32 W[g][k] -> bf16 kq-plane-major chunks (contiguous staged slices)
// ---------------------------------------------------------------------------
__global__ void pack_w_kernel(const float* __restrict__ src,
                              unsigned short* __restrict__ dst, int lgBW) {
    int idx = blockIdx.x * 256 + threadIdx.x;   // total G*64 chunks
    int g = idx >> 6, kq = idx & 63;
    int nb = g >> lgBW, gl = g & ((1 << lgBW) - 1);
    const float* s = src + g * Ff + kq * 8;
    float4 a = *(const float4*)s, b = *(const float4*)(s + 4);
    uint4 pk = pack8(a.x, a.y, a.z, a.w, b.x, b.y, b.z, b.w);
    long long dc = (((long long)(nb << 6) + kq) << lgBW) + gl;
    *(uint4*)((char*)dst + dc * 16) = pk;
}

// ---------------------------------------------------------------------------
// Fused link MLP. Block = 64 rows (1 pair x 64 batches) x 512 cols, 512 thr,
// 8 waves, wave tile 64x64 (acc[2][2] = 64 VGPR). K_STEP = 16.
// E resident 64 KB (h1 in-place). W: 3-deep pipelined 16KB contiguous slices
// (packed layout) via gl_lds; counted s_waitcnt vmcnt(2) + raw s_barrier.
// LDS = 112 KB -> 1 block/CU; the vmcnt pipeline carries the latency hiding.
// Per step: 4 MFMA/wave vs 16KB stage -> 2x the MFMA density of the M=32 ver.
// ---------------------------------------------------------------------------
__global__ __launch_bounds__(512, 2) void link_kernel(
    const float* __restrict__ nf, const float* __restrict__ colp,
    const unsigned short* __restrict__ W1p, const float* __restrict__ b1,
    const unsigned short* __restrict__ W2p, const float* __restrict__ b2,
    const float* __restrict__ w_out, const float* __restrict__ b_out,
    float* __restrict__ adj, int mode)
{
    __shared__ __align__(16) char Eb[64 * 64 * 16];      // 65,536 B
    __shared__ __align__(16) char Wb[3][2 * 512 * 16];   // 3 x 16,384 B

    const int tid = threadIdx.x;
    const int pr  = blockIdx.x >> 4;
    const int bc  = blockIdx.x & 15;
    int pi, pj; pair_decode(mode, pr, pi, pj);

    const int wid = tid >> 6;
    const int l   = tid & 63;
    const int lr  = l & 31;
    const int kg  = l >> 5;

    // stage a 16KB W K-slice (contiguous in packed layout), async, no regs
    auto stageW = [&](int tgt) {   // tgt = global step index 0..63
        const unsigned short* Wsp = (tgt >= 32) ? W2p : W1p;
        const int kq0 = (tgt & 31) * 2;
        char* dstb = (char*)Wb[tgt % 3];
#pragma unroll
        for (int i = 0; i < 2; ++i) {
            int cb = i * 512 + wid * 64;           // wave-uniform chunk base
            gl_lds16(Wsp + (kq0 * 512 + cb + l) * 8, dstb + cb * 16);
        }
    };

    // ---- prime pipeline: slices 0 and 1 ----
    stageW(0);
    stageW(1);

    // ---- E build: row = tid>>3 (64 rows), kc = tid&7 covers 64 k ----
    {
        const int row = tid >> 3;
        const int kc  = tid & 7;
        const int b   = bc * 64 + row;
        const float* xi = (pi == Zi) ? (colp + b * Ff) : (nf + (b * Nn + pi) * Ff);
        const float* xj = (pj == Zi) ? (colp + b * Ff) : (nf + (b * Nn + pj) * Ff);
#pragma unroll
        for (int i = 0; i < 8; ++i) {
            const int k0 = kc * 64 + i * 8;
            const int plane = k0 >> 3;
            float4 u0 = *(const float4*)(xi + k0), u1 = *(const float4*)(xi + k0 + 4);
            float4 v0 = *(const float4*)(xj + k0), v1 = *(const float4*)(xj + k0 + 4);
            *(uint4*)(&Eb[(plane * 64 + row) * 16]) =
                pack8(u0.x*v0.x, u0.y*v0.y, u0.z*v0.z, u0.w*v0.w,
                      u1.x*v1.x, u1.y*v1.y, u1.z*v1.z, u1.w*v1.w);
        }
    }
    __syncthreads();    // drains stage 0,1 + E writes

    f32x16 acc[2][2];
#pragma unroll
    for (int m = 0; m < 2; ++m)
#pragma unroll
        for (int n = 0; n < 2; ++n) acc[m][n] = (f32x16)(0.f);

    const int c0 = wid * 64 + lr;
    const int c1 = c0 + 32;

#pragma unroll 1
    for (int gks = 0; gks < 64; ++gks) {
        // issue stage for step gks+2 (3-deep pipeline)
        if (gks + 2 < 64) stageW(gks + 2);

        // MFMA for this step (K=16): 64 rows x 64 cols per wave
        {
            const int ks = gks & 31;
            const int plane = ks * 2 + kg;
            bfrag a0 = *(const bfrag*)(&Eb[(plane * 64 + lr) * 16]);
            bfrag a1 = *(const bfrag*)(&Eb[(plane * 64 + 32 + lr) * 16]);
            const char* Wc = (const char*)Wb[gks % 3];
            bfrag w0 = *(const bfrag*)(Wc + (kg * 512 + c0) * 16);
            bfrag w1 = *(const bfrag*)(Wc + (kg * 512 + c1) * 16);
            acc[0][0] = __builtin_amdgcn_mfma_f32_32x32x16_bf16(a0, w0, acc[0][0], 0, 0, 0);
            acc[0][1] = __builtin_amdgcn_mfma_f32_32x32x16_bf16(a0, w1, acc[0][1], 0, 0, 0);
            acc[1][0] = __builtin_amdgcn_mfma_f32_32x32x16_bf16(a1, w0, acc[1][0], 0, 0, 0);
            acc[1][1] = __builtin_amdgcn_mfma_f32_32x32x16_bf16(a1, w1, acc[1][1], 0, 0, 0);
        }

        if (gks == 31) {
            // layer boundary: full sync (drains all stages), h1 in-place
            __syncthreads();
            float bv0 = b1[c0], bv1 = b1[c1];
#pragma unroll
            for (int n = 0; n < 2; ++n) {
                const int c  = n ? c1 : c0;
                const float bv = n ? bv1 : bv0;
#pragma unroll
                for (int m = 0; m < 2; ++m)
#pragma unroll
                    for (int reg = 0; reg < 16; ++reg) {
                        int row = m * 32 + (reg & 3) + 8 * (reg >> 2) + 4 * kg;
                        float v = fmaxf(acc[m][n][reg] + bv, 0.f);
                        *(unsigned short*)(&Eb[((c >> 3) * 64 + row) * 16 + (c & 7) * 2]) =
                            (unsigned short)f2bf(v);
                    }
            }
#pragma unroll
            for (int m = 0; m < 2; ++m)
#pragma unroll
                for (int n = 0; n < 2; ++n) acc[m][n] = (f32x16)(0.f);
            __syncthreads();
        } else if (gks == 62) {
            // no stage issued next step: need last slice (63) complete
            asm volatile("s_waitcnt vmcnt(0) lgkmcnt(0)" ::: "memory");
            __builtin_amdgcn_s_barrier();
            __builtin_amdgcn_sched_barrier(0);
        } else if (gks < 63) {
            // steady state: stages gks+1, gks+2 outstanding (4 loads);
            // wait for the older pair -> vmcnt(2); lgkmcnt(0) orders reuse.
            asm volatile("s_waitcnt vmcnt(2) lgkmcnt(0)" ::: "memory");
            __builtin_amdgcn_s_barrier();
            __builtin_amdgcn_sched_barrier(0);
        }
    }

    // ---- fused layer-3: rowsum of relu(acc+b2)*w_out ----
    float rs[2][16];
    {
        float bv0 = b2[c0], bv1 = b2[c1];
        float wv0 = w_out[c0], wv1 = w_out[c1];
#pragma unroll
        for (int m = 0; m < 2; ++m)
#pragma unroll
            for (int reg = 0; reg < 16; ++reg)
                rs[m][reg] = fmaxf(acc[m][0][reg] + bv0, 0.f) * wv0
                           + fmaxf(acc[m][1][reg] + bv1, 0.f) * wv1;
#pragma unroll
        for (int off = 1; off < 32; off <<= 1)
#pragma unroll
            for (int m = 0; m < 2; ++m)
#pragma unroll
                for (int reg = 0; reg < 16; ++reg)
                    rs[m][reg] += __shfl_xor(rs[m][reg], off);
    }
    __syncthreads();                       // all Wb reads done -> reuse as Pl
    float* Pl = (float*)&Wb[0][0];         // [8][64]
    if (lr == 0) {
#pragma unroll
        for (int m = 0; m < 2; ++m)
#pragma unroll
            for (int reg = 0; reg < 16; ++reg) {
                int row = m * 32 + (reg & 3) + 8 * (reg >> 2) + 4 * kg;
                Pl[wid * 64 + row] = rs[m][reg];
            }
    }
    __syncthreads();
    if (tid < 64) {
        float v = b_out[0];
#pragma unroll
        for (int w = 0; w < 8; ++w) v += Pl[w * 64 + tid];
        int b = bc * 64 + tid;
        adj[b * (Nn * Nn) + pi * Nn + pj] = v;
        if (pi != pj) adj[b * (Nn * Nn) + pj * Nn + pi] = v;
    }
}

// ---------------------------------------------------------------------------
__global__ void softmax_az_kernel(const float* __restrict__ adj, float* __restrict__ a_z) {
    int b = blockIdx.x * 256 + threadIdx.x;
    if (b >= Bsz) return;
    const float* row = adj + b * (Nn * Nn) + Zi * Nn;
    float mx = row[0];
#pragma unroll
    for (int j = 1; j < Nn; ++j) mx = fmaxf(mx, row[j]);
    float e[Nn]; float s = 0.f;
#pragma unroll
    for (int j = 0; j < Nn; ++j) { e[j] = expf(row[j] - mx); s += e[j]; }
    float inv = 1.f / s;
#pragma unroll
    for (int j = 0; j < Nn; ++j) a_z[b * Nn + j] = e[j] * inv;
}

__global__ void mfix_kernel(const float* __restrict__ nf, const float* __restrict__ a_z,
                            float* __restrict__ m_fix) {
    int idx = blockIdx.x * 256 + threadIdx.x;
    int b = idx >> 9, f = idx & 511;
    float s = 0.f;
#pragma unroll
    for (int j = 0; j < Nn - 1; ++j)
        s += a_z[b * Nn + j] * nf[(b * Nn + j) * Ff + f];
    m_fix[idx] = s;
}

// ---------------------------------------------------------------------------
// gates: gi = (m_fix + az*col) @ Wih^T ; gh = col @ Whh^T (fp32 out)
// ---------------------------------------------------------------------------
__global__ __launch_bounds__(256, 3) void gates_kernel(
    const float* __restrict__ m_fix, const float* __restrict__ a_z,
    const float* __restrict__ colp,
    const unsigned short* __restrict__ Wihp, const unsigned short* __restrict__ Whhp,
    float* __restrict__ gi, float* __restrict__ gh)
{
    __shared__ __align__(16) char Wb[2][4 * 128 * 16];   // 2 x 8,192 B
    __shared__ __align__(16) char Ab[2][4 * 64 * 16];    // 2 x 4,096 B

    const int xb = blockIdx.x, bc = blockIdx.y, tid = threadIdx.x;
    const bool isGi = xb < 12;
    const int nb = isGi ? xb : xb - 12;
    const unsigned short* Wp = isGi ? Wihp : Whhp;
    float* C = isGi ? gi : gh;

    const int wid = tid >> 6;
    const int l   = tid & 63;
    const int bloc = tid >> 2;
    const int kc   = tid & 3;
    const int b    = bc * 64 + bloc;
    const float* cs = colp + b * Ff;
    const float* mf = m_fix + b * Ff;
    const float azv = isGi ? a_z[b * Nn + Zi] : 0.f;

    uint4 areg;
    auto loadA = [&](int k0) {
        const float* pc = cs + k0 + kc * 8;
        float4 c0 = *(const float4*)pc, c1 = *(const float4*)(pc + 4);
        if (isGi) {
            const float* pm = mf + k0 + kc * 8;
            float4 m0 = *(const float4*)pm, m1 = *(const float4*)(pm + 4);
            areg = pack8(m0.x + azv*c0.x, m0.y + azv*c0.y, m0.z + azv*c0.z, m0.w + azv*c0.w,
                         m1.x + azv*c1.x, m1.y + azv*c1.y, m1.z + azv*c1.z, m1.w + azv*c1.w);
        } else {
            areg = pack8(c0.x, c0.y, c0.z, c0.w, c1.x, c1.y, c1.z, c1.w);
        }
    };
    auto stageW = [&](int ks, int buf) {
        const int base = nb * 8192 + ks * 4 * 128;
#pragma unroll
        for (int i = 0; i < 2; ++i) {
            int cb = i * 256 + wid * 64;
            gl_lds16(Wp + (base + cb + l) * 8, (char*)Wb[buf] + cb * 16);
        }
    };

    stageW(0, 0);
    loadA(0);
    *(uint4*)(&Ab[0][(kc * 64 + bloc) * 16]) = areg;
    __syncthreads();

    const int lr = l & 31;
    const int kg = l >> 5;

    f32x16 acc[2];
    acc[0] = (f32x16)(0.f);
    acc[1] = (f32x16)(0.f);

#pragma unroll 1
    for (int ks = 0; ks < 16; ++ks) {
        const int cur = ks & 1;
        if (ks < 15) {
            stageW(ks + 1, cur ^ 1);
            loadA((ks + 1) * 32);
        }
#pragma unroll
        for (int s = 0; s < 2; ++s) {
            const int kcv = 2 * s + kg;
            bfrag a0 = *(const bfrag*)(&Ab[cur][(kcv * 64 + lr) * 16]);
            bfrag a1 = *(const bfrag*)(&Ab[cur][(kcv * 64 + 32 + lr) * 16]);
            bfrag bf = *(const bfrag*)(&Wb[cur][(kcv * 128 + wid * 32 + lr) * 16]);
            acc[0] = __builtin_amdgcn_mfma_f32_32x32x16_bf16(a0, bf, acc[0], 0, 0, 0);
            acc[1] = __builtin_amdgcn_mfma_f32_32x32x16_bf16(a1, bf, acc[1], 0, 0, 0);
        }
        if (ks < 15)
            *(uint4*)(&Ab[cur ^ 1][(kc * 64 + bloc) * 16]) = areg;
        __syncthreads();
    }

    const int colg = nb * 128 + wid * 32 + lr;
#pragma unroll
    for (int m = 0; m < 2; ++m) {
#pragma unroll
        for (int reg = 0; reg < 16; ++reg) {
            int row = m * 32 + (reg & 3) + 8 * (reg >> 2) + 4 * kg;
            C[(bc * 64 + row) * G3 + colg] = acc[m][reg];
        }
    }
}

// ---------------------------------------------------------------------------
__global__ void gru_kernel(const float* __restrict__ gi, const float* __restrict__ gh,
                           float* __restrict__ col) {
    int idx = blockIdx.x * 256 + threadIdx.x;   // 4 f per thread
    int b = idx >> 7, f = (idx & 127) * 4;
    const float* gib = gi + b * G3;
    const float* ghb = gh + b * G3;
    float4 ir = *(const float4*)(gib + f);
    float4 iz = *(const float4*)(gib + Ff + f);
    float4 in = *(const float4*)(gib + 2 * Ff + f);
    float4 hr = *(const float4*)(ghb + f);
    float4 hz = *(const float4*)(ghb + Ff + f);
    float4 hn = *(const float4*)(ghb + 2 * Ff + f);
    float4 h  = *(const float4*)(col + b * Ff + f);
    float4 o;
#define GRU1(c) { \
    float r = 1.f / (1.f + expf(-(ir.c + hr.c))); \
    float z = 1.f / (1.f + expf(-(iz.c + hz.c))); \
    float n = tanhf(in.c + r * hn.c); \
    o.c = (1.f - z) * n + z * h.c; }
    GRU1(x) GRU1(y) GRU1(z) GRU1(w)
#undef GRU1
    *(float4*)(col + b * Ff + f) = o;
}

// ---------------------------------------------------------------------------
extern "C" void kernel_launch(void* const* d_in, const int* in_sizes, int n_in,
                              void* d_out, int out_size, void* d_ws, size_t ws_size,
                              hipStream_t stream) {
    const float* nf    = (const float*)d_in[0];
    const float* W1    = (const float*)d_in[1];
    const float* b1    = (const float*)d_in[2];
    const float* W2    = (const float*)d_in[3];
    const float* b2    = (const float*)d_in[4];
    const float* w_out = (const float*)d_in[5];
    const float* b_out = (const float*)d_in[6];
    const float* W_ih  = (const float*)d_in[7];
    const float* W_hh  = (const float*)d_in[8];

    float* adj = (float*)d_out;                 // (B, 11, 11)
    float* col = adj + Bsz * Nn * Nn;           // (B, 512)

    unsigned short* W1p  = (unsigned short*)d_ws;        // packed, 512*512
    unsigned short* W2p  = W1p + Ff * Ff;
    unsigned short* Wihp = W2p + Ff * Ff;                // packed, 1536*512
    unsigned short* Whhp = Wihp + G3 * Ff;
    float* a_z   = (float*)(Whhp + G3 * Ff);
    float* m_fix = a_z + 16384;
    float* gi    = m_fix + Bsz * Ff;
    float* gh    = gi + Bsz * G3;

    init_col_kernel<<<(Bsz * Ff) / 256, 256, 0, stream>>>(nf, col);
    pack_w_kernel<<<(Ff * 64) / 256, 256, 0, stream>>>(W1, W1p, 9);
    pack_w_kernel<<<(Ff * 64) / 256, 256, 0, stream>>>(W2, W2p, 9);
    pack_w_kernel<<<(G3 * 64) / 256, 256, 0, stream>>>(W_ih, Wihp, 7);
    pack_w_kernel<<<(G3 * 64) / 256, 256, 0, stream>>>(W_hh, Whhp, 7);

    for (int t = 0; t < 3; ++t) {
        const int mode   = (t == 0) ? 0 : 1;
        const int npairs = (t == 0) ? 66 : 11;

        link_kernel<<<npairs * 16, 512, 0, stream>>>(nf, col, W1p, b1, W2p, b2,
                                                     w_out, b_out, adj, mode);
        softmax_az_kernel<<<Bsz / 256, 256, 0, stream>>>(adj, a_z);
        mfix_kernel<<<(Bsz * Ff) / 256, 256, 0, stream>>>(nf, a_z, m_fix);

        for (int s = 0; s < 3; ++s) {
            gates_kernel<<<dim3(24, 16), 256, 0, stream>>>(m_fix, a_z, col,
                                                           Wihp, Whhp, gi, gh);
            gru_kernel<<<(Bsz * Ff) / 4 / 256, 256, 0, stream>>>(gi, gh, col);
        }
    }
}

// Round 14
// 498.049 us; speedup vs baseline: 1.1435x; 1.1435x over previous
//
#include <hip/hip_runtime.h>
#include <hip/hip_bf16.h>
#include <math.h>

#define Bsz 1024
#define Nn  11
#define Ff  512
#define Zi  10
#define G3  1536

#define PEC 65    // Eb plane stride (64 rows + 1 pad chunk)
#define PWC 513   // Wb plane stride (512 cols + 1 pad chunk)

typedef __attribute__((ext_vector_type(8))) short bfrag;
typedef __attribute__((ext_vector_type(4))) float f32x4;
typedef __attribute__((ext_vector_type(16))) float f32x16;

__device__ __forceinline__ unsigned f2bf(float f) {
    __hip_bfloat16 h = __float2bfloat16(f);
    return (unsigned)*reinterpret_cast<unsigned short*>(&h);
}
__device__ __forceinline__ uint4 pack8(float v0, float v1, float v2, float v3,
                                       float v4, float v5, float v6, float v7) {
    uint4 pk;
    pk.x = f2bf(v0) | (f2bf(v1) << 16);
    pk.y = f2bf(v2) | (f2bf(v3) << 16);
    pk.z = f2bf(v4) | (f2bf(v5) << 16);
    pk.w = f2bf(v6) | (f2bf(v7) << 16);
    return pk;
}
__device__ __forceinline__ void pair_decode(int mode, int p, int& pi, int& pj) {
    if (mode == 0) { int r = p, i = 0; while (r >= Nn - i) { r -= Nn - i; ++i; } pi = i; pj = i + r; }
    else { pi = p; pj = Zi; }
}
// async global->LDS, 16B/lane; dst must be wave-uniform base (+lane*16 by HW)
__device__ __forceinline__ void gl_lds16(const void* src, void* dst) {
    __builtin_amdgcn_global_load_lds((const __attribute__((address_space(1))) void*)src,
                                     (__attribute__((address_space(3))) void*)dst, 16, 0, 0);
}

// ---------------------------------------------------------------------------
__global__ void init_col_kernel(const float* __restrict__ nf, float* __restrict__ col) {
    int idx = blockIdx.x * 256 + threadIdx.x;
    int b = idx >> 9, f = idx & 511;
    col[idx] = nf[(b * Nn + Zi) * Ff + f];
}

// ---------------------------------------------------------------------------
// pack fp32 W[g][k] -> bf16 kq-plane-major chunks (contiguous staged slices)
// ---------------------------------------------------------------------------
__global__ void pack_w_kernel(const float* __restrict__ src,
                              unsigned short* __restrict__ dst, int lgBW) {
    int idx = blockIdx.x * 256 + threadIdx.x;   // total G*64 chunks
    int g = idx >> 6, kq = idx & 63;
    int nb = g >> lgBW, gl = g & ((1 << lgBW) - 1);
    const float* s = src + g * Ff + kq * 8;
    float4 a = *(const float4*)s, b = *(const float4*)(s + 4);
    uint4 pk = pack8(a.x, a.y, a.z, a.w, b.x, b.y, b.z, b.w);
    long long dc = (((long long)(nb << 6) + kq) << lgBW) + gl;
    *(uint4*)((char*)dst + dc * 16) = pk;
}

// ---------------------------------------------------------------------------
// Fused link MLP, m97 geometry. Block = 64 rows (1 pair x 64 batches) x 512
// cols, 512 thr / 8 waves; wave tile 64x64 = 4x4 of mfma_f32_16x16x32_bf16
// (acc = 64 VGPR, 8 ds_read_b128 -> 16 MFMA per step, ratio 0.5).
// K_STEP = 32 -> 32 steps total (half the barriers of the 32x32 version).
// E resident 65 KB padded (h1 in-place); W dbuf 2x32.8 KB staged contiguous
// (packed kq-major) via global_load_lds. 134 KB LDS -> 1 block/CU.
// ---------------------------------------------------------------------------
__global__ __launch_bounds__(512, 2) void link_kernel(
    const float* __restrict__ nf, const float* __restrict__ colp,
    const unsigned short* __restrict__ W1p, const float* __restrict__ b1,
    const unsigned short* __restrict__ W2p, const float* __restrict__ b2,
    const float* __restrict__ w_out, const float* __restrict__ b_out,
    float* __restrict__ adj, int mode)
{
    __shared__ __align__(16) char Eb[64 * PEC * 16];     // 66,560 B
    __shared__ __align__(16) char Wb[2][4 * PWC * 16];   // 2 x 32,832 B
    __shared__ float Pl[8][64];                          //  2,048 B

    const int tid = threadIdx.x;
    const int pr  = blockIdx.x >> 4;
    const int bc  = blockIdx.x & 15;
    int pi, pj; pair_decode(mode, pr, pi, pj);

    const int wid  = tid >> 6;
    const int l    = tid & 63;
    const int lr16 = l & 15;
    const int kq4  = l >> 4;     // 0..3 : k-octet group of the fragment

    // stage one 32KB W K-slice (4 kq-planes x 512 cols, contiguous src)
    auto stageW = [&](int tgt) {   // tgt = step index 0..31
        const unsigned short* Wsp = (tgt >= 16) ? W2p : W1p;
        const int kq0 = (tgt & 15) * 4;
        char* dstb = (char*)Wb[tgt & 1];
#pragma unroll
        for (int i = 0; i < 4; ++i) {
            gl_lds16(Wsp + ((kq0 + i) * 512 + wid * 64 + l) * 8,
                     dstb + (i * PWC + wid * 64) * 16);
        }
    };

    stageW(0);

    // ---- E build: row = tid>>3 (64 rows), kc = tid&7 covers 64 k each ----
    {
        const int row = tid >> 3;
        const int kc  = tid & 7;
        const int b   = bc * 64 + row;
        const float* xi = (pi == Zi) ? (colp + b * Ff) : (nf + (b * Nn + pi) * Ff);
        const float* xj = (pj == Zi) ? (colp + b * Ff) : (nf + (b * Nn + pj) * Ff);
#pragma unroll
        for (int i = 0; i < 8; ++i) {
            const int k0 = kc * 64 + i * 8;
            const int plane = k0 >> 3;
            float4 u0 = *(const float4*)(xi + k0), u1 = *(const float4*)(xi + k0 + 4);
            float4 v0 = *(const float4*)(xj + k0), v1 = *(const float4*)(xj + k0 + 4);
            *(uint4*)(&Eb[(plane * PEC + row) * 16]) =
                pack8(u0.x*v0.x, u0.y*v0.y, u0.z*v0.z, u0.w*v0.w,
                      u1.x*v1.x, u1.y*v1.y, u1.z*v1.z, u1.w*v1.w);
        }
    }
    __syncthreads();    // drains stage 0 + E writes

    f32x4 acc[4][4];
#pragma unroll
    for (int mt = 0; mt < 4; ++mt)
#pragma unroll
        for (int nt = 0; nt < 4; ++nt) acc[mt][nt] = (f32x4){0.f, 0.f, 0.f, 0.f};

#pragma unroll 1
    for (int s = 0; s < 32; ++s) {
        if (s + 1 < 32) stageW(s + 1);

        // A-frags: 4 x 16-row groups; lane reads rows mt*16+lr16, k-octet kq4
        const int ebase = (s & 15) * 4 + kq4;
        bfrag a0 = *(const bfrag*)(&Eb[(ebase * PEC +      lr16) * 16]);
        bfrag a1 = *(const bfrag*)(&Eb[(ebase * PEC + 16 + lr16) * 16]);
        bfrag a2 = *(const bfrag*)(&Eb[(ebase * PEC + 32 + lr16) * 16]);
        bfrag a3 = *(const bfrag*)(&Eb[(ebase * PEC + 48 + lr16) * 16]);
        const char* Wc = (const char*)Wb[s & 1];
        bfrag w0 = *(const bfrag*)(Wc + (kq4 * PWC + wid * 64 +      lr16) * 16);
        bfrag w1 = *(const bfrag*)(Wc + (kq4 * PWC + wid * 64 + 16 + lr16) * 16);
        bfrag w2 = *(const bfrag*)(Wc + (kq4 * PWC + wid * 64 + 32 + lr16) * 16);
        bfrag w3 = *(const bfrag*)(Wc + (kq4 * PWC + wid * 64 + 48 + lr16) * 16);

#define MF(mt, A) \
        acc[mt][0] = __builtin_amdgcn_mfma_f32_16x16x32_bf16(A, w0, acc[mt][0], 0, 0, 0); \
        acc[mt][1] = __builtin_amdgcn_mfma_f32_16x16x32_bf16(A, w1, acc[mt][1], 0, 0, 0); \
        acc[mt][2] = __builtin_amdgcn_mfma_f32_16x16x32_bf16(A, w2, acc[mt][2], 0, 0, 0); \
        acc[mt][3] = __builtin_amdgcn_mfma_f32_16x16x32_bf16(A, w3, acc[mt][3], 0, 0, 0);
        MF(0, a0) MF(1, a1) MF(2, a2) MF(3, a3)
#undef MF

        if (s == 15) {
            __syncthreads();   // all E reads done (also drains stage 16)
            // h1 = relu(acc + b1) -> Eb in place
#pragma unroll
            for (int nt = 0; nt < 4; ++nt) {
                const int c  = wid * 64 + nt * 16 + lr16;
                const float bv = b1[c];
#pragma unroll
                for (int mt = 0; mt < 4; ++mt)
#pragma unroll
                    for (int reg = 0; reg < 4; ++reg) {
                        int row = mt * 16 + kq4 * 4 + reg;
                        float v = fmaxf(acc[mt][nt][reg] + bv, 0.f);
                        *(unsigned short*)(&Eb[((c >> 3) * PEC + row) * 16 + (c & 7) * 2]) =
                            (unsigned short)f2bf(v);
                    }
            }
#pragma unroll
            for (int mt = 0; mt < 4; ++mt)
#pragma unroll
                for (int nt = 0; nt < 4; ++nt) acc[mt][nt] = (f32x4){0.f, 0.f, 0.f, 0.f};
            __syncthreads();
        } else {
            __syncthreads();   // stage s+1 complete + Wb[s&1] reads done
        }
    }

    // ---- fused layer-3: rowsum of relu(acc+b2)*w_out ----
    {
        float rs[4][4];   // [mt][reg]
#pragma unroll
        for (int mt = 0; mt < 4; ++mt)
#pragma unroll
            for (int reg = 0; reg < 4; ++reg) rs[mt][reg] = 0.f;
#pragma unroll
        for (int nt = 0; nt < 4; ++nt) {
            const int c  = wid * 64 + nt * 16 + lr16;
            const float bv = b2[c];
            const float wv = w_out[c];
#pragma unroll
            for (int mt = 0; mt < 4; ++mt)
#pragma unroll
                for (int reg = 0; reg < 4; ++reg)
                    rs[mt][reg] += fmaxf(acc[mt][nt][reg] + bv, 0.f) * wv;
        }
        // reduce across the 16 lanes (same row, different cols)
#pragma unroll
        for (int off = 1; off < 16; off <<= 1)
#pragma unroll
            for (int mt = 0; mt < 4; ++mt)
#pragma unroll
                for (int reg = 0; reg < 4; ++reg)
                    rs[mt][reg] += __shfl_xor(rs[mt][reg], off);
        if (lr16 == 0) {
#pragma unroll
            for (int mt = 0; mt < 4; ++mt)
#pragma unroll
                for (int reg = 0; reg < 4; ++reg) {
                    int row = mt * 16 + kq4 * 4 + reg;
                    Pl[wid][row] = rs[mt][reg];
                }
        }
    }
    __syncthreads();
    if (tid < 64) {
        float v = b_out[0];
#pragma unroll
        for (int w = 0; w < 8; ++w) v += Pl[w][tid];
        int b = bc * 64 + tid;
        adj[b * (Nn * Nn) + pi * Nn + pj] = v;
        if (pi != pj) adj[b * (Nn * Nn) + pj * Nn + pi] = v;
    }
}

// ---------------------------------------------------------------------------
__global__ void softmax_az_kernel(const float* __restrict__ adj, float* __restrict__ a_z) {
    int b = blockIdx.x * 256 + threadIdx.x;
    if (b >= Bsz) return;
    const float* row = adj + b * (Nn * Nn) + Zi * Nn;
    float mx = row[0];
#pragma unroll
    for (int j = 1; j < Nn; ++j) mx = fmaxf(mx, row[j]);
    float e[Nn]; float s = 0.f;
#pragma unroll
    for (int j = 0; j < Nn; ++j) { e[j] = expf(row[j] - mx); s += e[j]; }
    float inv = 1.f / s;
#pragma unroll
    for (int j = 0; j < Nn; ++j) a_z[b * Nn + j] = e[j] * inv;
}

__global__ void mfix_kernel(const float* __restrict__ nf, const float* __restrict__ a_z,
                            float* __restrict__ m_fix) {
    int idx = blockIdx.x * 256 + threadIdx.x;
    int b = idx >> 9, f = idx & 511;
    float s = 0.f;
#pragma unroll
    for (int j = 0; j < Nn - 1; ++j)
        s += a_z[b * Nn + j] * nf[(b * Nn + j) * Ff + f];
    m_fix[idx] = s;
}

// ---------------------------------------------------------------------------
// gates: gi = (m_fix + az*col) @ Wih^T ; gh = col @ Whh^T (fp32 out)
// ---------------------------------------------------------------------------
__global__ __launch_bounds__(256, 3) void gates_kernel(
    const float* __restrict__ m_fix, const float* __restrict__ a_z,
    const float* __restrict__ colp,
    const unsigned short* __restrict__ Wihp, const unsigned short* __restrict__ Whhp,
    float* __restrict__ gi, float* __restrict__ gh)
{
    __shared__ __align__(16) char Wb[2][4 * 128 * 16];   // 2 x 8,192 B
    __shared__ __align__(16) char Ab[2][4 * 64 * 16];    // 2 x 4,096 B

    const int xb = blockIdx.x, bc = blockIdx.y, tid = threadIdx.x;
    const bool isGi = xb < 12;
    const int nb = isGi ? xb : xb - 12;
    const unsigned short* Wp = isGi ? Wihp : Whhp;
    float* C = isGi ? gi : gh;

    const int wid = tid >> 6;
    const int l   = tid & 63;
    const int bloc = tid >> 2;
    const int kc   = tid & 3;
    const int b    = bc * 64 + bloc;
    const float* cs = colp + b * Ff;
    const float* mf = m_fix + b * Ff;
    const float azv = isGi ? a_z[b * Nn + Zi] : 0.f;

    uint4 areg;
    auto loadA = [&](int k0) {
        const float* pc = cs + k0 + kc * 8;
        float4 c0 = *(const float4*)pc, c1 = *(const float4*)(pc + 4);
        if (isGi) {
            const float* pm = mf + k0 + kc * 8;
            float4 m0 = *(const float4*)pm, m1 = *(const float4*)(pm + 4);
            areg = pack8(m0.x + azv*c0.x, m0.y + azv*c0.y, m0.z + azv*c0.z, m0.w + azv*c0.w,
                         m1.x + azv*c1.x, m1.y + azv*c1.y, m1.z + azv*c1.z, m1.w + azv*c1.w);
        } else {
            areg = pack8(c0.x, c0.y, c0.z, c0.w, c1.x, c1.y, c1.z, c1.w);
        }
    };
    auto stageW = [&](int ks, int buf) {
        const int base = nb * 8192 + ks * 4 * 128;
#pragma unroll
        for (int i = 0; i < 2; ++i) {
            int cb = i * 256 + wid * 64;
            gl_lds16(Wp + (base + cb + l) * 8, (char*)Wb[buf] + cb * 16);
        }
    };

    stageW(0, 0);
    loadA(0);
    *(uint4*)(&Ab[0][(kc * 64 + bloc) * 16]) = areg;
    __syncthreads();

    const int lr = l & 31;
    const int kg = l >> 5;

    f32x16 acc[2];
    acc[0] = (f32x16)(0.f);
    acc[1] = (f32x16)(0.f);

#pragma unroll 1
    for (int ks = 0; ks < 16; ++ks) {
        const int cur = ks & 1;
        if (ks < 15) {
            stageW(ks + 1, cur ^ 1);
            loadA((ks + 1) * 32);
        }
#pragma unroll
        for (int s = 0; s < 2; ++s) {
            const int kcv = 2 * s + kg;
            bfrag a0 = *(const bfrag*)(&Ab[cur][(kcv * 64 + lr) * 16]);
            bfrag a1 = *(const bfrag*)(&Ab[cur][(kcv * 64 + 32 + lr) * 16]);
            bfrag bf = *(const bfrag*)(&Wb[cur][(kcv * 128 + wid * 32 + lr) * 16]);
            acc[0] = __builtin_amdgcn_mfma_f32_32x32x16_bf16(a0, bf, acc[0], 0, 0, 0);
            acc[1] = __builtin_amdgcn_mfma_f32_32x32x16_bf16(a1, bf, acc[1], 0, 0, 0);
        }
        if (ks < 15)
            *(uint4*)(&Ab[cur ^ 1][(kc * 64 + bloc) * 16]) = areg;
        __syncthreads();
    }

    const int colg = nb * 128 + wid * 32 + lr;
#pragma unroll
    for (int m = 0; m < 2; ++m) {
#pragma unroll
        for (int reg = 0; reg < 16; ++reg) {
            int row = m * 32 + (reg & 3) + 8 * (reg >> 2) + 4 * kg;
            C[(bc * 64 + row) * G3 + colg] = acc[m][reg];
        }
    }
}

// ---------------------------------------------------------------------------
__global__ void gru_kernel(const float* __restrict__ gi, const float* __restrict__ gh,
                           float* __restrict__ col) {
    int idx = blockIdx.x * 256 + threadIdx.x;   // 4 f per thread
    int b = idx >> 7, f = (idx & 127) * 4;
    const float* gib = gi + b * G3;
    const float* ghb = gh + b * G3;
    float4 ir = *(const float4*)(gib + f);
    float4 iz = *(const float4*)(gib + Ff + f);
    float4 in = *(const float4*)(gib + 2 * Ff + f);
    float4 hr = *(const float4*)(ghb + f);
    float4 hz = *(const float4*)(ghb + Ff + f);
    float4 hn = *(const float4*)(ghb + 2 * Ff + f);
    float4 h  = *(const float4*)(col + b * Ff + f);
    float4 o;
#define GRU1(c) { \
    float r = 1.f / (1.f + expf(-(ir.c + hr.c))); \
    float z = 1.f / (1.f + expf(-(iz.c + hz.c))); \
    float n = tanhf(in.c + r * hn.c); \
    o.c = (1.f - z) * n + z * h.c; }
    GRU1(x) GRU1(y) GRU1(z) GRU1(w)
#undef GRU1
    *(float4*)(col + b * Ff + f) = o;
}

// ---------------------------------------------------------------------------
extern "C" void kernel_launch(void* const* d_in, const int* in_sizes, int n_in,
                              void* d_out, int out_size, void* d_ws, size_t ws_size,
                              hipStream_t stream) {
    const float* nf    = (const float*)d_in[0];
    const float* W1    = (const float*)d_in[1];
    const float* b1    = (const float*)d_in[2];
    const float* W2    = (const float*)d_in[3];
    const float* b2    = (const float*)d_in[4];
    const float* w_out = (const float*)d_in[5];
    const float* b_out = (const float*)d_in[6];
    const float* W_ih  = (const float*)d_in[7];
    const float* W_hh  = (const float*)d_in[8];

    float* adj = (float*)d_out;                 // (B, 11, 11)
    float* col = adj + Bsz * Nn * Nn;           // (B, 512)

    unsigned short* W1p  = (unsigned short*)d_ws;        // packed, 512*512
    unsigned short* W2p  = W1p + Ff * Ff;
    unsigned short* Wihp = W2p + Ff * Ff;                // packed, 1536*512
    unsigned short* Whhp = Wihp + G3 * Ff;
    float* a_z   = (float*)(Whhp + G3 * Ff);
    float* m_fix = a_z + 16384;
    float* gi    = m_fix + Bsz * Ff;
    float* gh    = gi + Bsz * G3;

    init_col_kernel<<<(Bsz * Ff) / 256, 256, 0, stream>>>(nf, col);
    pack_w_kernel<<<(Ff * 64) / 256, 256, 0, stream>>>(W1, W1p, 9);
    pack_w_kernel<<<(Ff * 64) / 256, 256, 0, stream>>>(W2, W2p, 9);
    pack_w_kernel<<<(G3 * 64) / 256, 256, 0, stream>>>(W_ih, Wihp, 7);
    pack_w_kernel<<<(G3 * 64) / 256, 256, 0, stream>>>(W_hh, Whhp, 7);

    for (int t = 0; t < 3; ++t) {
        const int mode   = (t == 0) ? 0 : 1;
        const int npairs = (t == 0) ? 66 : 11;

        link_kernel<<<npairs * 16, 512, 0, stream>>>(nf, col, W1p, b1, W2p, b2,
                                                     w_out, b_out, adj, mode);
        softmax_az_kernel<<<Bsz / 256, 256, 0, stream>>>(adj, a_z);
        mfix_kernel<<<(Bsz * Ff) / 256, 256, 0, stream>>>(nf, a_z, m_fix);

        for (int s = 0; s < 3; ++s) {
            gates_kernel<<<dim3(24, 16), 256, 0, stream>>>(m_fix, a_z, col,
                                                           Wihp, Whhp, gi, gh);
            gru_kernel<<<(Bsz * Ff) / 4 / 256, 256, 0, stream>>>(gi, gh, col);
        }
    }
}

// Round 15
// 364.351 us; speedup vs baseline: 1.5631x; 1.3669x over previous
//
#include <hip/hip_runtime.h>
#include <hip/hip_bf16.h>
#include <math.h>

#define Bsz 1024
#define Nn  11
#define Ff  512
#define Zi  10
#define G3  1536

#define PEC 65    // Eb plane stride (64 rows + 1 pad chunk)

typedef __attribute__((ext_vector_type(8))) short bfrag;
typedef __attribute__((ext_vector_type(4))) float f32x4;

__device__ __forceinline__ unsigned f2bf(float f) {
    __hip_bfloat16 h = __float2bfloat16(f);
    return (unsigned)*reinterpret_cast<unsigned short*>(&h);
}
__device__ __forceinline__ uint4 pack8(float v0, float v1, float v2, float v3,
                                       float v4, float v5, float v6, float v7) {
    uint4 pk;
    pk.x = f2bf(v0) | (f2bf(v1) << 16);
    pk.y = f2bf(v2) | (f2bf(v3) << 16);
    pk.z = f2bf(v4) | (f2bf(v5) << 16);
    pk.w = f2bf(v6) | (f2bf(v7) << 16);
    return pk;
}
__device__ __forceinline__ void pair_decode(int mode, int p, int& pi, int& pj) {
    if (mode == 0) { int r = p, i = 0; while (r >= Nn - i) { r -= Nn - i; ++i; } pi = i; pj = i + r; }
    else { pi = p; pj = Zi; }
}
// async global->LDS, 16B/lane; dst must be wave-uniform base (+lane*16 by HW)
__device__ __forceinline__ void gl_lds16(const void* src, void* dst) {
    __builtin_amdgcn_global_load_lds((const __attribute__((address_space(1))) void*)src,
                                     (__attribute__((address_space(3))) void*)dst, 16, 0, 0);
}

// ---------------------------------------------------------------------------
__global__ void init_col_kernel(const float* __restrict__ nf, float* __restrict__ col) {
    int idx = blockIdx.x * 256 + threadIdx.x;
    int b = idx >> 9, f = idx & 511;
    col[idx] = nf[(b * Nn + Zi) * Ff + f];
}

// ---------------------------------------------------------------------------
// pack fp32 W[g][k] -> bf16 kq-plane-major chunks (contiguous/coalescable)
// ---------------------------------------------------------------------------
__global__ void pack_w_kernel(const float* __restrict__ src,
                              unsigned short* __restrict__ dst, int lgBW) {
    int idx = blockIdx.x * 256 + threadIdx.x;   // total G*64 chunks
    int g = idx >> 6, kq = idx & 63;
    int nb = g >> lgBW, gl = g & ((1 << lgBW) - 1);
    const float* s = src + g * Ff + kq * 8;
    float4 a = *(const float4*)s, b = *(const float4*)(s + 4);
    uint4 pk = pack8(a.x, a.y, a.z, a.w, b.x, b.y, b.z, b.w);
    long long dc = (((long long)(nb << 6) + kq) << lgBW) + gl;
    *(uint4*)((char*)dst + dc * 16) = pk;
}

// ---------------------------------------------------------------------------
// Fused link MLP, barrier-free steady state. Block = 64 rows x 512 cols,
// 512 thr / 8 waves; wave tile 64x64 = 4x4 of mfma_f32_16x16x32_bf16.
// E resident in LDS (the only cross-wave-shared operand); W fragments loaded
// DIRECTLY global->VGPR (each wave owns its 64 cols - no sharing), ping-pong
// prefetched one step ahead. 3 barriers total (E build, h1 boundary x2).
// LDS 68.6 KB.
// ---------------------------------------------------------------------------
__global__ __launch_bounds__(512, 2) void link_kernel(
    const float* __restrict__ nf, const float* __restrict__ colp,
    const unsigned short* __restrict__ W1p, const float* __restrict__ b1,
    const unsigned short* __restrict__ W2p, const float* __restrict__ b2,
    const float* __restrict__ w_out, const float* __restrict__ b_out,
    float* __restrict__ adj, int mode)
{
    __shared__ __align__(16) char Eb[64 * PEC * 16];     // 66,560 B
    __shared__ float Pl[8][64];                          //  2,048 B

    const int tid = threadIdx.x;
    const int pr  = blockIdx.x >> 4;
    const int bc  = blockIdx.x & 15;
    int pi, pj; pair_decode(mode, pr, pi, pj);

    const int wid  = tid >> 6;
    const int l    = tid & 63;
    const int lr16 = l & 15;
    const int kq4  = l >> 4;

    const bfrag* W1c = (const bfrag*)W1p;
    const bfrag* W2c = (const bfrag*)W2p;
    const int wcb = wid * 64 + lr16;

    bfrag wb0[4], wb1[4];
    auto loadW = [&](int gs, bfrag* dst) {   // gs = global step 0..31
        const bfrag* Wc = (gs >= 16) ? W2c : W1c;
        const int base = ((gs & 15) * 4 + kq4) * 512 + wcb;
#pragma unroll
        for (int nt = 0; nt < 4; ++nt) dst[nt] = Wc[base + nt * 16];
    };

    loadW(0, wb0);

    // ---- E build: row = tid>>3 (64 rows), kc = tid&7 covers 64 k each ----
    {
        const int row = tid >> 3;
        const int kc  = tid & 7;
        const int b   = bc * 64 + row;
        const float* xi = (pi == Zi) ? (colp + b * Ff) : (nf + (b * Nn + pi) * Ff);
        const float* xj = (pj == Zi) ? (colp + b * Ff) : (nf + (b * Nn + pj) * Ff);
#pragma unroll
        for (int i = 0; i < 8; ++i) {
            const int k0 = kc * 64 + i * 8;
            const int plane = k0 >> 3;
            float4 u0 = *(const float4*)(xi + k0), u1 = *(const float4*)(xi + k0 + 4);
            float4 v0 = *(const float4*)(xj + k0), v1 = *(const float4*)(xj + k0 + 4);
            *(uint4*)(&Eb[(plane * PEC + row) * 16]) =
                pack8(u0.x*v0.x, u0.y*v0.y, u0.z*v0.z, u0.w*v0.w,
                      u1.x*v1.x, u1.y*v1.y, u1.z*v1.z, u1.w*v1.w);
        }
    }
    __syncthreads();    // E published

    f32x4 acc[4][4];
#pragma unroll
    for (int mt = 0; mt < 4; ++mt)
#pragma unroll
        for (int nt = 0; nt < 4; ++nt) acc[mt][nt] = (f32x4){0.f, 0.f, 0.f, 0.f};

#define DO_STEP(S, WB) { \
    const int ebase = ((S) & 15) * 4 + kq4; \
    bfrag a0 = *(const bfrag*)(&Eb[(ebase * PEC +      lr16) * 16]); \
    bfrag a1 = *(const bfrag*)(&Eb[(ebase * PEC + 16 + lr16) * 16]); \
    bfrag a2 = *(const bfrag*)(&Eb[(ebase * PEC + 32 + lr16) * 16]); \
    bfrag a3 = *(const bfrag*)(&Eb[(ebase * PEC + 48 + lr16) * 16]); \
    acc[0][0] = __builtin_amdgcn_mfma_f32_16x16x32_bf16(a0, WB[0], acc[0][0], 0, 0, 0); \
    acc[0][1] = __builtin_amdgcn_mfma_f32_16x16x32_bf16(a0, WB[1], acc[0][1], 0, 0, 0); \
    acc[0][2] = __builtin_amdgcn_mfma_f32_16x16x32_bf16(a0, WB[2], acc[0][2], 0, 0, 0); \
    acc[0][3] = __builtin_amdgcn_mfma_f32_16x16x32_bf16(a0, WB[3], acc[0][3], 0, 0, 0); \
    acc[1][0] = __builtin_amdgcn_mfma_f32_16x16x32_bf16(a1, WB[0], acc[1][0], 0, 0, 0); \
    acc[1][1] = __builtin_amdgcn_mfma_f32_16x16x32_bf16(a1, WB[1], acc[1][1], 0, 0, 0); \
    acc[1][2] = __builtin_amdgcn_mfma_f32_16x16x32_bf16(a1, WB[2], acc[1][2], 0, 0, 0); \
    acc[1][3] = __builtin_amdgcn_mfma_f32_16x16x32_bf16(a1, WB[3], acc[1][3], 0, 0, 0); \
    acc[2][0] = __builtin_amdgcn_mfma_f32_16x16x32_bf16(a2, WB[0], acc[2][0], 0, 0, 0); \
    acc[2][1] = __builtin_amdgcn_mfma_f32_16x16x32_bf16(a2, WB[1], acc[2][1], 0, 0, 0); \
    acc[2][2] = __builtin_amdgcn_mfma_f32_16x16x32_bf16(a2, WB[2], acc[2][2], 0, 0, 0); \
    acc[2][3] = __builtin_amdgcn_mfma_f32_16x16x32_bf16(a2, WB[3], acc[2][3], 0, 0, 0); \
    acc[3][0] = __builtin_amdgcn_mfma_f32_16x16x32_bf16(a3, WB[0], acc[3][0], 0, 0, 0); \
    acc[3][1] = __builtin_amdgcn_mfma_f32_16x16x32_bf16(a3, WB[1], acc[3][1], 0, 0, 0); \
    acc[3][2] = __builtin_amdgcn_mfma_f32_16x16x32_bf16(a3, WB[2], acc[3][2], 0, 0, 0); \
    acc[3][3] = __builtin_amdgcn_mfma_f32_16x16x32_bf16(a3, WB[3], acc[3][3], 0, 0, 0); }

    // ---- layer 1: steps 0..15 (no barriers) ----
#pragma unroll 1
    for (int s2 = 0; s2 < 8; ++s2) {
        const int s = 2 * s2;
        loadW(s + 1, wb1);
        DO_STEP(s, wb0)
        loadW(s + 2, wb0);           // s2==7 -> slice 16 = W2 slice 0
        DO_STEP(s + 1, wb1)
    }

    // ---- layer boundary: h1 = relu(acc+b1) -> Eb in place ----
    __syncthreads();                 // all layer-1 E reads done
    {
#pragma unroll
        for (int nt = 0; nt < 4; ++nt) {
            const int c  = wid * 64 + nt * 16 + lr16;
            const float bv = b1[c];
#pragma unroll
            for (int mt = 0; mt < 4; ++mt)
#pragma unroll
                for (int reg = 0; reg < 4; ++reg) {
                    int row = mt * 16 + kq4 * 4 + reg;
                    float v = fmaxf(acc[mt][nt][reg] + bv, 0.f);
                    *(unsigned short*)(&Eb[((c >> 3) * PEC + row) * 16 + (c & 7) * 2]) =
                        (unsigned short)f2bf(v);
                }
        }
#pragma unroll
        for (int mt = 0; mt < 4; ++mt)
#pragma unroll
            for (int nt = 0; nt < 4; ++nt) acc[mt][nt] = (f32x4){0.f, 0.f, 0.f, 0.f};
    }
    __syncthreads();                 // h1 published

    // ---- layer 2: steps 16..31 (no barriers) ----
#pragma unroll 1
    for (int s2 = 0; s2 < 8; ++s2) {
        const int s = 16 + 2 * s2;
        loadW(s + 1, wb1);
        DO_STEP(s, wb0)
        if (s2 < 7) loadW(s + 2, wb0);
        DO_STEP(s + 1, wb1)
    }
#undef DO_STEP

    // ---- fused layer-3: rowsum of relu(acc+b2)*w_out ----
    {
        float rs[4][4];
#pragma unroll
        for (int mt = 0; mt < 4; ++mt)
#pragma unroll
            for (int reg = 0; reg < 4; ++reg) rs[mt][reg] = 0.f;
#pragma unroll
        for (int nt = 0; nt < 4; ++nt) {
            const int c  = wid * 64 + nt * 16 + lr16;
            const float bv = b2[c];
            const float wv = w_out[c];
#pragma unroll
            for (int mt = 0; mt < 4; ++mt)
#pragma unroll
                for (int reg = 0; reg < 4; ++reg)
                    rs[mt][reg] += fmaxf(acc[mt][nt][reg] + bv, 0.f) * wv;
        }
#pragma unroll
        for (int off = 1; off < 16; off <<= 1)
#pragma unroll
            for (int mt = 0; mt < 4; ++mt)
#pragma unroll
                for (int reg = 0; reg < 4; ++reg)
                    rs[mt][reg] += __shfl_xor(rs[mt][reg], off);
        if (lr16 == 0) {
#pragma unroll
            for (int mt = 0; mt < 4; ++mt)
#pragma unroll
                for (int reg = 0; reg < 4; ++reg) {
                    int row = mt * 16 + kq4 * 4 + reg;
                    Pl[wid][row] = rs[mt][reg];
                }
        }
    }
    __syncthreads();
    if (tid < 64) {
        float v = b_out[0];
#pragma unroll
        for (int w = 0; w < 8; ++w) v += Pl[w][tid];
        int b = bc * 64 + tid;
        adj[b * (Nn * Nn) + pi * Nn + pj] = v;
        if (pi != pj) adj[b * (Nn * Nn) + pj * Nn + pi] = v;
    }
}

// ---------------------------------------------------------------------------
__global__ void softmax_az_kernel(const float* __restrict__ adj, float* __restrict__ a_z) {
    int b = blockIdx.x * 256 + threadIdx.x;
    if (b >= Bsz) return;
    const float* row = adj + b * (Nn * Nn) + Zi * Nn;
    float mx = row[0];
#pragma unroll
    for (int j = 1; j < Nn; ++j) mx = fmaxf(mx, row[j]);
    float e[Nn]; float s = 0.f;
#pragma unroll
    for (int j = 0; j < Nn; ++j) { e[j] = expf(row[j] - mx); s += e[j]; }
    float inv = 1.f / s;
#pragma unroll
    for (int j = 0; j < Nn; ++j) a_z[b * Nn + j] = e[j] * inv;
}

// ---------------------------------------------------------------------------
// mzpack: m_z[b,f] = sum_{j<10} az[j]*nf[b,j,f] + az[10]*col[b,f]
// writes m_z AND col as bf16 in kq-plane-major packed layout (per 64-row
// block rb: chunk dc = (rb*64 + kq)*64 + r) for gates' gl_lds staging.
// ---------------------------------------------------------------------------
__global__ void mzpack_kernel(const float* __restrict__ nf, const float* __restrict__ a_z,
                              const float* __restrict__ col,
                              unsigned short* __restrict__ m_zp,
                              unsigned short* __restrict__ colbf) {
    int idx = blockIdx.x * 256 + threadIdx.x;   // Bsz*64
    int b = idx >> 6, kq = idx & 63;
    const float* az = a_z + b * Nn;
    const int f0 = kq * 8;
    float4 c0 = *(const float4*)(col + b * Ff + f0);
    float4 c1 = *(const float4*)(col + b * Ff + f0 + 4);
    float az10 = az[Zi];
    float s0 = az10 * c0.x, s1 = az10 * c0.y, s2 = az10 * c0.z, s3 = az10 * c0.w;
    float s4 = az10 * c1.x, s5 = az10 * c1.y, s6 = az10 * c1.z, s7 = az10 * c1.w;
#pragma unroll
    for (int j = 0; j < Nn - 1; ++j) {
        float aj = az[j];
        const float* p = nf + (b * Nn + j) * Ff + f0;
        float4 n0 = *(const float4*)p, n1 = *(const float4*)(p + 4);
        s0 += aj * n0.x; s1 += aj * n0.y; s2 += aj * n0.z; s3 += aj * n0.w;
        s4 += aj * n1.x; s5 += aj * n1.y; s6 += aj * n1.z; s7 += aj * n1.w;
    }
    long long dc = (((long long)(b >> 6) * 64 + kq) << 6) + (b & 63);
    *(uint4*)((char*)m_zp + dc * 16)  = pack8(s0, s1, s2, s3, s4, s5, s6, s7);
    *(uint4*)((char*)colbf + dc * 16) = pack8(c0.x, c0.y, c0.z, c0.w, c1.x, c1.y, c1.z, c1.w);
}

// ---------------------------------------------------------------------------
// gates: gi = m_z @ Wih^T ; gh = col @ Whh^T (fp32 out). Block = 64 rows x
// 256 cols, 256 thr / 4 waves, wave tile 64x64. A staged ONCE (64KB, gl_lds
// contiguous from packed layout); W direct global->VGPR ping-pong. Steady
// state barrier-free. grid (12, 16): xb<6 -> gi, else gh.
// ---------------------------------------------------------------------------
__global__ __launch_bounds__(256, 2) void gates_kernel(
    const unsigned short* __restrict__ m_zp, const unsigned short* __restrict__ colbf,
    const unsigned short* __restrict__ Wihp, const unsigned short* __restrict__ Whhp,
    float* __restrict__ gi, float* __restrict__ gh)
{
    __shared__ __align__(16) char Ab[64 * 64 * 16];   // 65,536 B

    const int xb = blockIdx.x, bc = blockIdx.y, tid = threadIdx.x;
    const bool isGi = xb < 6;
    const int nbase = (isGi ? xb : xb - 6) * 256;
    const unsigned short* Ap = isGi ? m_zp : colbf;
    const unsigned short* Wp = isGi ? Wihp : Whhp;
    float* C = isGi ? gi : gh;

    const int wid  = tid >> 6;
    const int l    = tid & 63;
    const int lr16 = l & 15;
    const int kq4  = l >> 4;

    const bfrag* Wc = (const bfrag*)Wp;
    const int wcb = ((nbase >> 9) << 15) + (nbase & 511) + wid * 64 + lr16;

    bfrag wb0[4], wb1[4];
    auto loadW = [&](int s, bfrag* dst) {   // s = step 0..15
        const int base = wcb + (s * 4 + kq4) * 512;
#pragma unroll
        for (int nt = 0; nt < 4; ++nt) dst[nt] = Wc[base + nt * 16];
    };

    loadW(0, wb0);

    // ---- stage A (64 KB contiguous, async, no regs) ----
#pragma unroll
    for (int i = 0; i < 16; ++i) {
        int cb = i * 256 + wid * 64;
        gl_lds16(Ap + ((long long)bc * 4096 + cb + l) * 8, (char*)Ab + cb * 16);
    }
    __syncthreads();   // drains gl_lds + W slice 0

    f32x4 acc[4][4];
#pragma unroll
    for (int mt = 0; mt < 4; ++mt)
#pragma unroll
        for (int nt = 0; nt < 4; ++nt) acc[mt][nt] = (f32x4){0.f, 0.f, 0.f, 0.f};

#define DO_STEPG(S, WB) { \
    const int ebase = (S) * 4 + kq4; \
    bfrag a0 = *(const bfrag*)(&Ab[(ebase * 64 +      lr16) * 16]); \
    bfrag a1 = *(const bfrag*)(&Ab[(ebase * 64 + 16 + lr16) * 16]); \
    bfrag a2 = *(const bfrag*)(&Ab[(ebase * 64 + 32 + lr16) * 16]); \
    bfrag a3 = *(const bfrag*)(&Ab[(ebase * 64 + 48 + lr16) * 16]); \
    acc[0][0] = __builtin_amdgcn_mfma_f32_16x16x32_bf16(a0, WB[0], acc[0][0], 0, 0, 0); \
    acc[0][1] = __builtin_amdgcn_mfma_f32_16x16x32_bf16(a0, WB[1], acc[0][1], 0, 0, 0); \
    acc[0][2] = __builtin_amdgcn_mfma_f32_16x16x32_bf16(a0, WB[2], acc[0][2], 0, 0, 0); \
    acc[0][3] = __builtin_amdgcn_mfma_f32_16x16x32_bf16(a0, WB[3], acc[0][3], 0, 0, 0); \
    acc[1][0] = __builtin_amdgcn_mfma_f32_16x16x32_bf16(a1, WB[0], acc[1][0], 0, 0, 0); \
    acc[1][1] = __builtin_amdgcn_mfma_f32_16x16x32_bf16(a1, WB[1], acc[1][1], 0, 0, 0); \
    acc[1][2] = __builtin_amdgcn_mfma_f32_16x16x32_bf16(a1, WB[2], acc[1][2], 0, 0, 0); \
    acc[1][3] = __builtin_amdgcn_mfma_f32_16x16x32_bf16(a1, WB[3], acc[1][3], 0, 0, 0); \
    acc[2][0] = __builtin_amdgcn_mfma_f32_16x16x32_bf16(a2, WB[0], acc[2][0], 0, 0, 0); \
    acc[2][1] = __builtin_amdgcn_mfma_f32_16x16x32_bf16(a2, WB[1], acc[2][1], 0, 0, 0); \
    acc[2][2] = __builtin_amdgcn_mfma_f32_16x16x32_bf16(a2, WB[2], acc[2][2], 0, 0, 0); \
    acc[2][3] = __builtin_amdgcn_mfma_f32_16x16x32_bf16(a2, WB[3], acc[2][3], 0, 0, 0); \
    acc[3][0] = __builtin_amdgcn_mfma_f32_16x16x32_bf16(a3, WB[0], acc[3][0], 0, 0, 0); \
    acc[3][1] = __builtin_amdgcn_mfma_f32_16x16x32_bf16(a3, WB[1], acc[3][1], 0, 0, 0); \
    acc[3][2] = __builtin_amdgcn_mfma_f32_16x16x32_bf16(a3, WB[2], acc[3][2], 0, 0, 0); \
    acc[3][3] = __builtin_amdgcn_mfma_f32_16x16x32_bf16(a3, WB[3], acc[3][3], 0, 0, 0); }

#pragma unroll 1
    for (int s2 = 0; s2 < 8; ++s2) {
        const int s = 2 * s2;
        loadW(s + 1, wb1);
        DO_STEPG(s, wb0)
        if (s2 < 7) loadW(s + 2, wb0);
        DO_STEPG(s + 1, wb1)
    }
#undef DO_STEPG

    // ---- epilogue: fp32 stores ----
#pragma unroll
    for (int nt = 0; nt < 4; ++nt) {
        const int c = nbase + wid * 64 + nt * 16 + lr16;
#pragma unroll
        for (int mt = 0; mt < 4; ++mt)
#pragma unroll
            for (int reg = 0; reg < 4; ++reg) {
                int row = mt * 16 + kq4 * 4 + reg;
                C[(bc * 64 + row) * G3 + c] = acc[mt][nt][reg];
            }
    }
}

// ---------------------------------------------------------------------------
__global__ void gru_kernel(const float* __restrict__ gi, const float* __restrict__ gh,
                           float* __restrict__ col) {
    int idx = blockIdx.x * 256 + threadIdx.x;   // 4 f per thread
    int b = idx >> 7, f = (idx & 127) * 4;
    const float* gib = gi + b * G3;
    const float* ghb = gh + b * G3;
    float4 ir = *(const float4*)(gib + f);
    float4 iz = *(const float4*)(gib + Ff + f);
    float4 in = *(const float4*)(gib + 2 * Ff + f);
    float4 hr = *(const float4*)(ghb + f);
    float4 hz = *(const float4*)(ghb + Ff + f);
    float4 hn = *(const float4*)(ghb + 2 * Ff + f);
    float4 h  = *(const float4*)(col + b * Ff + f);
    float4 o;
#define GRU1(c) { \
    float r = 1.f / (1.f + expf(-(ir.c + hr.c))); \
    float z = 1.f / (1.f + expf(-(iz.c + hz.c))); \
    float n = tanhf(in.c + r * hn.c); \
    o.c = (1.f - z) * n + z * h.c; }
    GRU1(x) GRU1(y) GRU1(z) GRU1(w)
#undef GRU1
    *(float4*)(col + b * Ff + f) = o;
}

// ---------------------------------------------------------------------------
extern "C" void kernel_launch(void* const* d_in, const int* in_sizes, int n_in,
                              void* d_out, int out_size, void* d_ws, size_t ws_size,
                              hipStream_t stream) {
    const float* nf    = (const float*)d_in[0];
    const float* W1    = (const float*)d_in[1];
    const float* b1    = (const float*)d_in[2];
    const float* W2    = (const float*)d_in[3];
    const float* b2    = (const float*)d_in[4];
    const float* w_out = (const float*)d_in[5];
    const float* b_out = (const float*)d_in[6];
    const float* W_ih  = (const float*)d_in[7];
    const float* W_hh  = (const float*)d_in[8];

    float* adj = (float*)d_out;                 // (B, 11, 11)
    float* col = adj + Bsz * Nn * Nn;           // (B, 512)

    unsigned short* W1p   = (unsigned short*)d_ws;       // packed, 512*512
    unsigned short* W2p   = W1p + Ff * Ff;
    unsigned short* Wihp  = W2p + Ff * Ff;               // packed, 1536*512
    unsigned short* Whhp  = Wihp + G3 * Ff;
    float* a_z            = (float*)(Whhp + G3 * Ff);    // 16384 floats
    unsigned short* m_zp  = (unsigned short*)(a_z + 16384);   // B*512 bf16 packed
    unsigned short* colbf = m_zp + Bsz * Ff;                  // B*512 bf16 packed
    float* gi             = (float*)(colbf + Bsz * Ff);  // B*1536
    float* gh             = gi + Bsz * G3;               // B*1536

    init_col_kernel<<<(Bsz * Ff) / 256, 256, 0, stream>>>(nf, col);
    pack_w_kernel<<<(Ff * 64) / 256, 256, 0, stream>>>(W1, W1p, 9);
    pack_w_kernel<<<(Ff * 64) / 256, 256, 0, stream>>>(W2, W2p, 9);
    pack_w_kernel<<<(G3 * 64) / 256, 256, 0, stream>>>(W_ih, Wihp, 9);
    pack_w_kernel<<<(G3 * 64) / 256, 256, 0, stream>>>(W_hh, Whhp, 9);

    for (int t = 0; t < 3; ++t) {
        const int mode   = (t == 0) ? 0 : 1;
        const int npairs = (t == 0) ? 66 : 11;

        link_kernel<<<npairs * 16, 512, 0, stream>>>(nf, col, W1p, b1, W2p, b2,
                                                     w_out, b_out, adj, mode);
        softmax_az_kernel<<<Bsz / 256, 256, 0, stream>>>(adj, a_z);

        for (int s = 0; s < 3; ++s) {
            mzpack_kernel<<<(Bsz * 64) / 256, 256, 0, stream>>>(nf, a_z, col, m_zp, colbf);
            gates_kernel<<<dim3(12, 16), 256, 0, stream>>>(m_zp, colbf, Wihp, Whhp, gi, gh);
            gru_kernel<<<(Bsz * Ff) / 4 / 256, 256, 0, stream>>>(gi, gh, col);
        }
    }
}